// Round 23
// baseline (142.851 us; speedup 1.0000x reference)
//
#include <hip/hip_runtime.h>
#include <hip/hip_bf16.h>

#define BATCH 16
#define TLEN 2048
#define CDIM 1024
#define HDIM 128

typedef __attribute__((ext_vector_type(8))) short bf16x8;
typedef __attribute__((ext_vector_type(4))) float f32x4;
typedef __attribute__((ext_vector_type(16))) float f32x16;
typedef __attribute__((ext_vector_type(4))) unsigned short u16x4;
typedef __attribute__((ext_vector_type(8))) unsigned short u16x8;

static __device__ __forceinline__ unsigned short f2bf(float f) {
    __hip_bfloat16 h = __float2bfloat16(f);
    return *(unsigned short*)&h;
}
static __device__ __forceinline__ unsigned pkbf(float a, float b) {
    return (unsigned)f2bf(a) | ((unsigned)f2bf(b) << 16);
}
// KV-chunk = 512 keys.  partials per (b,qc) prefix: sum_{j<qc} (j/4 + 1)
static __device__ __forceinline__ int part_offs(int qc) {
    const int g = qc >> 2;
    return qc + 2 * g * (g - 1) + (qc & 3) * g;
}

typedef const __attribute__((address_space(1))) unsigned int* gas_t;
typedef __attribute__((address_space(3))) unsigned int* las_t;
static __device__ __forceinline__ void gl_lds16(const void* g, void* l) {
    __builtin_amdgcn_global_load_lds((gas_t)g, (las_t)l, 16, 0, 0);
}

// raw barrier pinned against compiler reordering (rule 18 / m201 pattern)
static __device__ __forceinline__ void hard_barrier() {
    __builtin_amdgcn_sched_barrier(0);
    __builtin_amdgcn_s_barrier();
    __builtin_amdgcn_sched_barrier(0);
}

// ---------------------------------------------------------------------------
// Prep: pack Wq|Wk|Wv into transposed bf16  wtb[(which*128+n)*1024 + k].
// ---------------------------------------------------------------------------
__global__ __launch_bounds__(256) void pack_w(
    const float* __restrict__ Wq, const float* __restrict__ Wk,
    const float* __restrict__ Wv, unsigned short* __restrict__ wtb)
{
    const int which = blockIdx.y;
    const float* W = (which == 0) ? Wq : (which == 1) ? Wk : Wv;
    const int n = blockIdx.x >> 2;
    const int k = (blockIdx.x & 3) * 256 + threadIdx.x;
    wtb[((size_t)which * 128 + n) * 1024 + k] = f2bf(W[(size_t)k * 128 + n]);
}

// ---------------------------------------------------------------------------
// Kernel 1: FUSED QKV projection — r16 A-path, B IN REGISTERS (no B LDS).
// BM=128, BN=192, BK=64, 512 thr / 8 waves (2m x 4n, 64x48), grid 512,
// XCD-paired.  A: fp32 reg-staged -> cvt -> swizzled ds_write (T14 split);
// single barrier per step covers ONLY the A tile.  B: 6 contiguous 16B
// register loads per thread per step, straight from L2 (wtb row-major =
// fragment layout); compiler-managed counted waits.  LDS 32KB (was 80KB).
// ---------------------------------------------------------------------------
__global__ __launch_bounds__(512, 4) void qkv_fused(
    const float* __restrict__ x, const unsigned short* __restrict__ wtb,
    unsigned short* __restrict__ qb, unsigned short* __restrict__ kb,
    unsigned short* __restrict__ vtb)
{
    __shared__ __align__(16) unsigned short Ab[2][128 * 64];   // 2 x 16KB [m][k] bf16

    const int xcd = blockIdx.x & 7, s = blockIdx.x >> 3;
    const int m0 = (xcd * 32 + (s >> 1)) * 128;
    const int nh = s & 1;

    const int tid  = threadIdx.x;
    const int lane = tid & 63, wid = tid >> 6;
    const int wm = wid >> 2, wn = wid & 3;
    const int c = lane & 15, g = lane >> 4;

    const int arow = tid >> 2, aq = tid & 3;
    const float* xsrc = x + (size_t)(m0 + arow) * CDIM + aq * 16;
    // B fragment base: row (nh*192 + wn*48 + c), k chunk g*8; fragment (nf,ks)
    // adds nf*16 rows (nf*16384 elems) and ks*32 k.
    const unsigned short* wsrc = wtb + (size_t)(nh * 192 + wn * 48 + c) * 1024 + g * 8;

    f32x4 acc[4][3];
#pragma unroll
    for (int i = 0; i < 4; ++i)
#pragma unroll
        for (int j = 0; j < 3; ++j) acc[i][j] = (f32x4){0.f, 0.f, 0.f, 0.f};

    float4 As0, As1, As2, As3;
    bf16x8 Br[6];   // [nf*2 + ks], static indices only

#define AISSUE(k0_)                                                          \
    { const float* s_ = xsrc + (k0_);                                        \
      As0 = *(const float4*)(s_);      As1 = *(const float4*)(s_ + 4);       \
      As2 = *(const float4*)(s_ + 8);  As3 = *(const float4*)(s_ + 12); }

#define AWRITE(bi_)                                                          \
    { u16x8 t0_, t1_;                                                        \
      t0_[0]=f2bf(As0.x); t0_[1]=f2bf(As0.y); t0_[2]=f2bf(As0.z); t0_[3]=f2bf(As0.w); \
      t0_[4]=f2bf(As1.x); t0_[5]=f2bf(As1.y); t0_[6]=f2bf(As1.z); t0_[7]=f2bf(As1.w); \
      t1_[0]=f2bf(As2.x); t1_[1]=f2bf(As2.y); t1_[2]=f2bf(As2.z); t1_[3]=f2bf(As2.w); \
      t1_[4]=f2bf(As3.x); t1_[5]=f2bf(As3.y); t1_[6]=f2bf(As3.z); t1_[7]=f2bf(As3.w); \
      char* ba_ = (char*)Ab[bi_] + arow * 128;                               \
      *(u16x8*)(ba_ + ((aq * 32 +  0) ^ ((arow & 7) << 4))) = t0_;           \
      *(u16x8*)(ba_ + ((aq * 32 + 16) ^ ((arow & 7) << 4))) = t1_; }

#define BLOAD(k0_)                                                           \
    { _Pragma("unroll")                                                      \
      for (int f_ = 0; f_ < 6; ++f_)                                         \
          Br[f_] = *(const bf16x8*)(wsrc + (size_t)(f_ >> 1) * 16384 +       \
                                    (k0_) + (f_ & 1) * 32); }

    AISSUE(0);
    asm volatile("s_waitcnt vmcnt(0)" ::: "memory");
    AWRITE(0);
    asm volatile("s_waitcnt lgkmcnt(0)" ::: "memory");
    hard_barrier();

#pragma unroll 1
    for (int kt = 0; kt < 16; ++kt) {
        const int cur = kt & 1;
        BLOAD(kt * 64);                      // current step's B -> regs (L2)
        if (kt < 15) AISSUE((kt + 1) * 64);  // next step's A -> regs (HBM)

        // ---- compute tile kt: A from LDS (swizzled), B from registers ----
#pragma unroll
        for (int ks = 0; ks < 2; ++ks) {
            bf16x8 af[4];
#pragma unroll
            for (int mf = 0; mf < 4; ++mf) {
                const int rm = wm * 64 + mf * 16 + c;
                af[mf] = *(const bf16x8*)((char*)Ab[cur] + rm * 128 +
                                          ((ks * 64 + g * 16) ^ ((rm & 7) << 4)));
            }
            __builtin_amdgcn_s_setprio(1);
#pragma unroll
            for (int mf = 0; mf < 4; ++mf)
#pragma unroll
                for (int nf = 0; nf < 3; ++nf)
                    acc[mf][nf] = __builtin_amdgcn_mfma_f32_16x16x32_bf16(
                        af[mf], Br[nf * 2 + ks], acc[mf][nf], 0, 0, 0);
            __builtin_amdgcn_s_setprio(0);
        }

        if (kt < 15) {
            AWRITE(cur ^ 1);                 // compiler waits As via counted vmcnt
            asm volatile("s_waitcnt lgkmcnt(0)" ::: "memory");
            hard_barrier();                  // barrier scope: A tile only
        }
    }

    // ---- epilogue: per-fragment route to q (scaled) / k / v^T ----
#pragma unroll
    for (int mf = 0; mf < 4; ++mf) {
#pragma unroll
        for (int nf = 0; nf < 3; ++nf) {
            const int col0 = nh * 192 + wn * 48 + nf * 16;
            const int nt = col0 >> 7;
            const int nc = (col0 & 127) + c;
            const int m = m0 + wm * 64 + mf * 16 + g * 4;
            if (nt == 0) {
#pragma unroll
                for (int r = 0; r < 4; ++r)
                    qb[(size_t)(m + r) * HDIM + nc] = f2bf(acc[mf][nf][r] * 0.03125f);
            } else if (nt == 1) {
#pragma unroll
                for (int r = 0; r < 4; ++r)
                    kb[(size_t)(m + r) * HDIM + nc] = f2bf(acc[mf][nf][r]);
            } else {
                const int b = m >> 11, tl = m & (TLEN - 1);
                u16x4 o;
                o[0] = f2bf(acc[mf][nf][0]); o[1] = f2bf(acc[mf][nf][1]);
                o[2] = f2bf(acc[mf][nf][2]); o[3] = f2bf(acc[mf][nf][3]);
                *(u16x4*)(vtb + ((size_t)b * HDIM + nc) * TLEN + tl) = o;
            }
        }
    }
#undef AISSUE
#undef AWRITE
#undef BLOAD
}

// ---------------------------------------------------------------------------
// Kernel 2a: flash-attention partials (r17/r20/r22 — best measured, FROZEN).
// ---------------------------------------------------------------------------
__global__ __launch_bounds__(256, 2) void attn_partial(
    const short* __restrict__ qb, const short* __restrict__ kb,
    const short* __restrict__ vtb,
    unsigned short* __restrict__ Opart, float* __restrict__ mpart,
    float* __restrict__ lpart)
{
    const int kc = blockIdx.x;          // 0..3   (512-key chunk)
    const int qc = blockIdx.y;          // 0..15  (128-row chunk)
    const int b  = blockIdx.z;
    if (kc > (qc >> 2)) return;
    const int kv_base = kc * 512;
    const int qrel = qc * 128 - kv_base;
    int NT = (qrel >> 6) + 2; if (NT > 8) NT = 8;

    __shared__ unsigned short Ks[2][64 * 128];
    __shared__ unsigned short Vs[2][128 * 64];

    const int tid  = threadIdx.x;
    const int wid  = tid >> 6;
    const int lane = tid & 63;
    const int c5 = lane & 31, hi = lane >> 5;
    const int q0w = qc * 128 + wid * 32;
    const int qg  = q0w + c5;
    const int pidx = b * 40 + part_offs(qc) + kc;

    const short* Kb  = kb  + (size_t)b * TLEN * HDIM;
    const short* Vtb = vtb + (size_t)b * HDIM * TLEN;

    bf16x8 qf[8];
#pragma unroll
    for (int ks = 0; ks < 8; ++ks)
        qf[ks] = *(const bf16x8*)(qb + ((size_t)b * TLEN + qg) * HDIM + ks * 16 + hi * 8);

    bf16x8 kst[4], vst[4];

#define GLOAD(kv0_)                                                          \
    {                                                                        \
        _Pragma("unroll")                                                    \
        for (int it = 0; it < 4; ++it) {                                     \
            const int o = tid * 16 + it * 4096;                              \
            const int kr = o >> 8, kcb = o & 0xF0;                           \
            kst[it] = *(const bf16x8*)((const char*)Kb +                     \
                        (size_t)((kv0_) + kr) * 256 + kcb);                  \
            const int vr = o >> 7, vcb = o & 0x70;                           \
            vst[it] = *(const bf16x8*)((const char*)Vtb +                    \
                        (size_t)vr * (TLEN * 2) + (size_t)(kv0_) * 2 + vcb); \
        }                                                                    \
    }
#define SSTORE(bi_)                                                          \
    {                                                                        \
        _Pragma("unroll")                                                    \
        for (int it = 0; it < 4; ++it) {                                     \
            const int o = tid * 16 + it * 4096;                              \
            const int kr = o >> 8, kcb = o & 0xF0;                           \
            *(bf16x8*)((char*)Ks[bi_] + kr * 256 + (kcb ^ ((kr & 7) << 4))) = kst[it]; \
            const int vr = o >> 7, vcb = o & 0x70;                           \
            *(bf16x8*)((char*)Vs[bi_] + vr * 128 + (vcb ^ ((vr & 7) << 4))) = vst[it]; \
        }                                                                    \
    }

    GLOAD(kv_base);
    SSTORE(0);
    __syncthreads();

    f32x16 oacc[4];
#pragma unroll
    for (int i = 0; i < 4; ++i)
#pragma unroll
        for (int r = 0; r < 16; ++r) oacc[i][r] = 0.f;
    float m_r = -1e30f;
    float l_r = 0.f;

#pragma unroll 1
    for (int t = 0; t < NT; ++t) {
        const int bi = t & 1;
        if (t + 1 < NT) GLOAD(kv_base + 64 * (t + 1));

        const int kv0 = kv_base + 64 * t;
        if (kv0 <= q0w + 31) {
            f32x16 s0, s1;
#pragma unroll
            for (int r = 0; r < 16; ++r) { s0[r] = 0.f; s1[r] = 0.f; }
            __builtin_amdgcn_s_setprio(1);
#pragma unroll
            for (int ks = 0; ks < 8; ++ks) {
                const int col = ks * 32 + hi * 16;
                const int off0 = c5 * 256 + (col ^ ((c5 & 7) << 4));
                const int off1 = (32 + c5) * 256 + (col ^ ((c5 & 7) << 4));
                bf16x8 a0 = *(const bf16x8*)((char*)Ks[bi] + off0);
                bf16x8 a1 = *(const bf16x8*)((char*)Ks[bi] + off1);
                s0 = __builtin_amdgcn_mfma_f32_32x32x16_bf16(a0, qf[ks], s0, 0, 0, 0);
                s1 = __builtin_amdgcn_mfma_f32_32x32x16_bf16(a1, qf[ks], s1, 0, 0, 0);
            }
            __builtin_amdgcn_s_setprio(0);

            if (kv0 + 63 > q0w) {
#pragma unroll
                for (int r = 0; r < 16; ++r) {
                    const int key0 = kv0 + (r & 3) + 8 * (r >> 2) + 4 * hi;
                    if (key0 > qg)      s0[r] = -INFINITY;
                    if (key0 + 32 > qg) s1[r] = -INFINITY;
                }
            }

            float t8[8];
#pragma unroll
            for (int i = 0; i < 8; ++i)
                t8[i] = fmaxf(fmaxf(s0[2*i], s0[2*i+1]), fmaxf(s1[2*i], s1[2*i+1]));
            float smax = fmaxf(fmaxf(fmaxf(t8[0], t8[1]), fmaxf(t8[2], t8[3])),
                               fmaxf(fmaxf(t8[4], t8[5]), fmaxf(t8[6], t8[7])));
            smax = fmaxf(smax, __shfl_xor(smax, 32));

            const bool defer = __all(smax - m_r <= 8.0f);   // T13
            const float mnew = defer ? m_r : fmaxf(m_r, smax);
            if (!defer) {
                const float alpha = __expf(m_r - mnew);
                l_r *= alpha;
#pragma unroll
                for (int hb = 0; hb < 4; ++hb) oacc[hb] = oacc[hb] * alpha;
            }
            m_r = mnew;

#pragma unroll
            for (int r = 0; r < 16; ++r) {
                s0[r] = __expf(s0[r] - mnew);
                s1[r] = __expf(s1[r] - mnew);
            }
            float a8[8];
#pragma unroll
            for (int i = 0; i < 8; ++i)
                a8[i] = (s0[2*i] + s0[2*i+1]) + (s1[2*i] + s1[2*i+1]);
            float psum = ((a8[0] + a8[1]) + (a8[2] + a8[3])) +
                         ((a8[4] + a8[5]) + (a8[6] + a8[7]));
            psum += __shfl_xor(psum, 32);
            l_r += psum;

            bf16x8 pa[4];
#pragma unroll
            for (int kb2 = 0; kb2 < 2; ++kb2) {
#pragma unroll
                for (int par = 0; par < 2; ++par) {
                    const int e = par * 8;
                    float v0, v1, v2, v3, v4, v5, v6, v7;
                    if (kb2 == 0) {
                        v0=s0[e+0]; v1=s0[e+1]; v2=s0[e+2]; v3=s0[e+3];
                        v4=s0[e+4]; v5=s0[e+5]; v6=s0[e+6]; v7=s0[e+7];
                    } else {
                        v0=s1[e+0]; v1=s1[e+1]; v2=s1[e+2]; v3=s1[e+3];
                        v4=s1[e+4]; v5=s1[e+5]; v6=s1[e+6]; v7=s1[e+7];
                    }
                    const unsigned w0 = pkbf(v0, v1), w1 = pkbf(v2, v3);
                    const unsigned w2 = pkbf(v4, v5), w3 = pkbf(v6, v7);
                    const unsigned X0 = hi ? w0 : w2;
                    const unsigned X1 = hi ? w1 : w3;
                    const unsigned R0 = (unsigned)__shfl_xor((int)X0, 32);
                    const unsigned R1 = (unsigned)__shfl_xor((int)X1, 32);
                    union { unsigned w[4]; bf16x8 v; } uu;
                    uu.w[0] = hi ? R0 : w0;  uu.w[1] = hi ? R1 : w1;
                    uu.w[2] = hi ? w2 : R0;  uu.w[3] = hi ? w3 : R1;
                    pa[kb2 * 2 + par] = uu.v;
                }
            }

            __builtin_amdgcn_s_setprio(1);
#pragma unroll
            for (int hb = 0; hb < 4; ++hb) {
                const int row = hb * 32 + c5;
#pragma unroll
                for (int ks = 0; ks < 4; ++ks) {
                    const int off = row * 128 + ((ks * 32 + hi * 16) ^ ((row & 7) << 4));
                    bf16x8 va = *(const bf16x8*)((char*)Vs[bi] + off);
                    oacc[hb] = __builtin_amdgcn_mfma_f32_32x32x16_bf16(va, pa[ks], oacc[hb], 0, 0, 0);
                }
            }
            __builtin_amdgcn_s_setprio(0);
        }

        if (t + 1 < NT) {
            SSTORE(bi ^ 1);
            __syncthreads();
        }
    }

    // ---- epilogue: transpose O via LDS, store partials bf16 ----
    __syncthreads();
    char* sl = (char*)Ks + wid * 8192;
#pragma unroll
    for (int hb = 0; hb < 4; ++hb)
#pragma unroll
        for (int rq = 0; rq < 4; ++rq) {
            u16x4 o4;
            o4[0] = f2bf(oacc[hb][rq * 4 + 0]);
            o4[1] = f2bf(oacc[hb][rq * 4 + 1]);
            o4[2] = f2bf(oacc[hb][rq * 4 + 2]);
            o4[3] = f2bf(oacc[hb][rq * 4 + 3]);
            const int off = c5 * 256 + ((hb * 64 + rq * 16 + hi * 8) ^ ((c5 & 7) << 4));
            *(u16x4*)(sl + off) = o4;
        }
    asm volatile("s_waitcnt lgkmcnt(0)" ::: "memory");
    __builtin_amdgcn_sched_barrier(0);

    const int qr = lane >> 1, hf = lane & 1;
    unsigned short* Og = Opart + (size_t)pidx * 128 * 128 +
                         (size_t)(wid * 32 + qr) * 128 + hf * 64;
#pragma unroll
    for (int i = 0; i < 8; ++i) {
        const int off = qr * 256 + ((hf * 128 + i * 16) ^ ((qr & 7) << 4));
        *(u16x8*)(Og + i * 8) = *(const u16x8*)(sl + off);
    }
    if (hi == 0) {
        mpart[(size_t)pidx * 128 + wid * 32 + c5] = m_r;
        lpart[(size_t)pidx * 128 + wid * 32 + c5] = l_r;
    }
#undef GLOAD
#undef SSTORE
}

// ---------------------------------------------------------------------------
// Kernel 2b: combine partials (r17/r20/r22 — FROZEN).
// ---------------------------------------------------------------------------
__global__ __launch_bounds__(256) void attn_combine(
    const unsigned short* __restrict__ Opart, const float* __restrict__ mpart,
    const float* __restrict__ lpart, float* __restrict__ out)
{
    const int qc = blockIdx.x;
    const int b  = blockIdx.y;
    const int n  = (qc >> 2) + 1;
    const int base = b * 40 + part_offs(qc);
    const int t   = threadIdx.x;
    const int row = t >> 1;
    const int d0  = (t & 1) * 64;

    float mv[4], lv[4];
#pragma unroll
    for (int p = 0; p < 4; ++p) {
        mv[p] = (p < n) ? mpart[(size_t)(base + p) * 128 + row] : -INFINITY;
        lv[p] = (p < n) ? lpart[(size_t)(base + p) * 128 + row] : 0.f;
    }
    float M = fmaxf(fmaxf(mv[0], mv[1]), fmaxf(mv[2], mv[3]));
    float L = 0.f;
    float wv[4];
#pragma unroll
    for (int p = 0; p < 4; ++p) {
        wv[p] = (p < n) ? __expf(mv[p] - M) : 0.f;
        L += wv[p] * lv[p];
    }

    float acc[64];
#pragma unroll
    for (int i = 0; i < 64; ++i) acc[i] = 0.f;

    for (int p = 0; p < n; ++p) {
        const float w = wv[p];
        const bf16x8* src = (const bf16x8*)(Opart +
            ((size_t)(base + p) * 128 + row) * 128 + d0);
#pragma unroll
        for (int j = 0; j < 8; ++j) {
            bf16x8 v = src[j];
#pragma unroll
            for (int e = 0; e < 8; ++e) {
                union { unsigned u; float f; } xx;
                xx.u = ((unsigned)(unsigned short)v[e]) << 16;
                acc[j * 8 + e] += w * xx.f;
            }
        }
    }

    const float invL = 1.f / L;
    float4* dst = (float4*)(out + ((size_t)(b * TLEN + qc * 128 + row)) * 128 + d0);
#pragma unroll
    for (int i = 0; i < 16; ++i)
        dst[i] = make_float4(acc[4*i] * invL, acc[4*i+1] * invL,
                             acc[4*i+2] * invL, acc[4*i+3] * invL);
}

extern "C" void kernel_launch(void* const* d_in, const int* in_sizes, int n_in,
                              void* d_out, int out_size, void* d_ws, size_t ws_size,
                              hipStream_t stream)
{
    const float* x  = (const float*)d_in[0];
    const float* Wq = (const float*)d_in[1];
    const float* Wk = (const float*)d_in[2];
    const float* Wv = (const float*)d_in[3];
    float* outp = (float*)d_out;

    const size_t per = (size_t)BATCH * TLEN * HDIM;      // 4,194,304
    unsigned short* qb  = (unsigned short*)d_ws;
    unsigned short* kb  = qb + per;
    unsigned short* vtb = kb + per;
    unsigned short* wtb = vtb + per;                     // 384*1024 bf16
    unsigned short* Opart = wtb + 384 * 1024;            // 640*128*128 bf16
    float* mpart = (float*)(Opart + (size_t)640 * 128 * 128);
    float* lpart = mpart + (size_t)640 * 128;

    dim3 gw(512, 3);
    pack_w<<<gw, 256, 0, stream>>>(Wq, Wk, Wv, wtb);

    qkv_fused<<<512, 512, 0, stream>>>(x, wtb, qb, kb, vtb);

    dim3 g2(4, 16, BATCH);
    attn_partial<<<g2, 256, 0, stream>>>((const short*)qb, (const short*)kb,
                                         (const short*)vtb, Opart, mpart, lpart);

    dim3 g3(16, BATCH);
    attn_combine<<<g3, 256, 0, stream>>>(Opart, mpart, lpart, outp);
}

// Round 24
// 112.839 us; speedup vs baseline: 1.2660x; 1.2660x over previous
//
#include <hip/hip_runtime.h>
#include <hip/hip_bf16.h>

#define BATCH 16
#define TLEN 2048
#define CDIM 1024
#define HDIM 128

typedef __attribute__((ext_vector_type(8))) short bf16x8;
typedef __attribute__((ext_vector_type(4))) float f32x4;
typedef __attribute__((ext_vector_type(16))) float f32x16;
typedef __attribute__((ext_vector_type(4))) unsigned short u16x4;
typedef __attribute__((ext_vector_type(8))) unsigned short u16x8;

static __device__ __forceinline__ unsigned short f2bf(float f) {
    __hip_bfloat16 h = __float2bfloat16(f);
    return *(unsigned short*)&h;
}
static __device__ __forceinline__ unsigned pkbf(float a, float b) {
    return (unsigned)f2bf(a) | ((unsigned)f2bf(b) << 16);
}
// KV-chunk = 512 keys.  partials per (b,qc) prefix: sum_{j<qc} (j/4 + 1)
static __device__ __forceinline__ int part_offs(int qc) {
    const int g = qc >> 2;
    return qc + 2 * g * (g - 1) + (qc & 3) * g;
}

typedef const __attribute__((address_space(1))) unsigned int* gas_t;
typedef __attribute__((address_space(3))) unsigned int* las_t;
static __device__ __forceinline__ void gl_lds16(const void* g, void* l) {
    __builtin_amdgcn_global_load_lds((gas_t)g, (las_t)l, 16, 0, 0);
}

// raw barrier pinned against compiler reordering (rule 18 / m201 pattern)
static __device__ __forceinline__ void hard_barrier() {
    __builtin_amdgcn_sched_barrier(0);
    __builtin_amdgcn_s_barrier();
    __builtin_amdgcn_sched_barrier(0);
}

// ---------------------------------------------------------------------------
// Prep: pack Wq|Wk|Wv into transposed bf16  wtb[(which*128+n)*1024 + k].
// ---------------------------------------------------------------------------
__global__ __launch_bounds__(256) void pack_w(
    const float* __restrict__ Wq, const float* __restrict__ Wk,
    const float* __restrict__ Wv, unsigned short* __restrict__ wtb)
{
    const int which = blockIdx.y;
    const float* W = (which == 0) ? Wq : (which == 1) ? Wk : Wv;
    const int n = blockIdx.x >> 2;
    const int k = (blockIdx.x & 3) * 256 + threadIdx.x;
    wtb[((size_t)which * 128 + n) * 1024 + k] = f2bf(W[(size_t)k * 128 + n]);
}

// ---------------------------------------------------------------------------
// Kernel 1: FUSED QKV projection (r16 — best measured, ~78us).
// BM=128, BN=192, BK=64, 512 thr / 8 waves, grid 512, XCD-paired.
// A: fp32 reg-staged -> cvt -> swizzled ds_write (T14 split).
// B: gl_lds w16 pre-swizzled.  Counted vmcnt; one barrier/step; setprio.
// ---------------------------------------------------------------------------
__global__ __launch_bounds__(512, 4) void qkv_fused(
    const float* __restrict__ x, const unsigned short* __restrict__ wtb,
    unsigned short* __restrict__ qb, unsigned short* __restrict__ kb,
    unsigned short* __restrict__ vtb)
{
    __shared__ __align__(16) unsigned short Ab[2][128 * 64];   // 2 x 16KB [m][k] bf16
    __shared__ __align__(16) unsigned short Bb[2][192 * 64];   // 2 x 24KB [n][k] bf16

    const int xcd = blockIdx.x & 7, s = blockIdx.x >> 3;
    const int m0 = (xcd * 32 + (s >> 1)) * 128;
    const int nh = s & 1;

    const int tid  = threadIdx.x;
    const int lane = tid & 63, wid = tid >> 6;
    const int wm = wid >> 2, wn = wid & 3;
    const int c = lane & 15, g = lane >> 4;

    const int arow = tid >> 2, aq = tid & 3;
    const float* xsrc = x + (size_t)(m0 + arow) * CDIM + aq * 16;

    f32x4 acc[4][3];
#pragma unroll
    for (int i = 0; i < 4; ++i)
#pragma unroll
        for (int j = 0; j < 3; ++j) acc[i][j] = (f32x4){0.f, 0.f, 0.f, 0.f};

    float4 As0, As1, As2, As3;

#define AISSUE(k0_)                                                          \
    { const float* s_ = xsrc + (k0_);                                        \
      As0 = *(const float4*)(s_);      As1 = *(const float4*)(s_ + 4);       \
      As2 = *(const float4*)(s_ + 8);  As3 = *(const float4*)(s_ + 12); }

#define AWRITE(bi_)                                                          \
    { u16x8 t0_, t1_;                                                        \
      t0_[0]=f2bf(As0.x); t0_[1]=f2bf(As0.y); t0_[2]=f2bf(As0.z); t0_[3]=f2bf(As0.w); \
      t0_[4]=f2bf(As1.x); t0_[5]=f2bf(As1.y); t0_[6]=f2bf(As1.z); t0_[7]=f2bf(As1.w); \
      t1_[0]=f2bf(As2.x); t1_[1]=f2bf(As2.y); t1_[2]=f2bf(As2.z); t1_[3]=f2bf(As2.w); \
      t1_[4]=f2bf(As3.x); t1_[5]=f2bf(As3.y); t1_[6]=f2bf(As3.z); t1_[7]=f2bf(As3.w); \
      char* ba_ = (char*)Ab[bi_] + arow * 128;                               \
      *(u16x8*)(ba_ + ((aq * 32 +  0) ^ ((arow & 7) << 4))) = t0_;           \
      *(u16x8*)(ba_ + ((aq * 32 + 16) ^ ((arow & 7) << 4))) = t1_; }

#define BISSUE(k0_, bi_)                                                     \
    { _Pragma("unroll")                                                      \
      for (int i_ = 0; i_ < 3; ++i_) {                                       \
          const int seg_ = wid * 3 + i_;                                     \
          const int row_ = seg_ * 8 + (lane >> 3);                           \
          const int gr_  = (lane & 7) ^ (row_ & 7);                          \
          gl_lds16(wtb + (size_t)(nh * 192 + row_) * 1024 + (k0_) + gr_ * 8, \
                   (char*)Bb[bi_] + seg_ * 1024);                            \
      } }

    AISSUE(0);
    BISSUE(0, 0);
    asm volatile("s_waitcnt vmcnt(3)" ::: "memory");
    AWRITE(0);
    asm volatile("s_waitcnt vmcnt(0) lgkmcnt(0)" ::: "memory");
    hard_barrier();

#pragma unroll 1
    for (int kt = 0; kt < 16; ++kt) {
        const int cur = kt & 1;
        if (kt < 15) {
            AISSUE((kt + 1) * 64);
            BISSUE((kt + 1) * 64, cur ^ 1);
        }

#pragma unroll
        for (int ks = 0; ks < 2; ++ks) {
            bf16x8 af[4], bf[3];
#pragma unroll
            for (int mf = 0; mf < 4; ++mf) {
                const int rm = wm * 64 + mf * 16 + c;
                af[mf] = *(const bf16x8*)((char*)Ab[cur] + rm * 128 +
                                          ((ks * 64 + g * 16) ^ ((rm & 7) << 4)));
            }
#pragma unroll
            for (int nf = 0; nf < 3; ++nf) {
                const int rn = wn * 48 + nf * 16 + c;
                bf[nf] = *(const bf16x8*)((char*)Bb[cur] + rn * 128 +
                                          ((ks * 64 + g * 16) ^ ((rn & 7) << 4)));
            }
            __builtin_amdgcn_s_setprio(1);
#pragma unroll
            for (int mf = 0; mf < 4; ++mf)
#pragma unroll
                for (int nf = 0; nf < 3; ++nf)
                    acc[mf][nf] = __builtin_amdgcn_mfma_f32_16x16x32_bf16(
                        af[mf], bf[nf], acc[mf][nf], 0, 0, 0);
            __builtin_amdgcn_s_setprio(0);
        }

        if (kt < 15) {
            asm volatile("s_waitcnt vmcnt(3)" ::: "memory");
            AWRITE(cur ^ 1);
            asm volatile("s_waitcnt vmcnt(0) lgkmcnt(0)" ::: "memory");
            hard_barrier();
        }
    }

#pragma unroll
    for (int mf = 0; mf < 4; ++mf) {
#pragma unroll
        for (int nf = 0; nf < 3; ++nf) {
            const int col0 = nh * 192 + wn * 48 + nf * 16;
            const int nt = col0 >> 7;
            const int nc = (col0 & 127) + c;
            const int m = m0 + wm * 64 + mf * 16 + g * 4;
            if (nt == 0) {
#pragma unroll
                for (int r = 0; r < 4; ++r)
                    qb[(size_t)(m + r) * HDIM + nc] = f2bf(acc[mf][nf][r] * 0.03125f);
            } else if (nt == 1) {
#pragma unroll
                for (int r = 0; r < 4; ++r)
                    kb[(size_t)(m + r) * HDIM + nc] = f2bf(acc[mf][nf][r]);
            } else {
                const int b = m >> 11, tl = m & (TLEN - 1);
                u16x4 o;
                o[0] = f2bf(acc[mf][nf][0]); o[1] = f2bf(acc[mf][nf][1]);
                o[2] = f2bf(acc[mf][nf][2]); o[3] = f2bf(acc[mf][nf][3]);
                *(u16x4*)(vtb + ((size_t)b * HDIM + nc) * TLEN + tl) = o;
            }
        }
    }
#undef AISSUE
#undef AWRITE
#undef BISSUE
}

// ---------------------------------------------------------------------------
// Kernel 2a: flash-attention partials (r17 — best measured).
// Task = (b, qc [128 q rows], kc [512 keys]), active iff kc <= qc/4.
// 4 waves, 32x32 swapped-operand, in-register softmax, defer-max.
// ---------------------------------------------------------------------------
__global__ __launch_bounds__(256, 2) void attn_partial(
    const short* __restrict__ qb, const short* __restrict__ kb,
    const short* __restrict__ vtb,
    unsigned short* __restrict__ Opart, float* __restrict__ mpart,
    float* __restrict__ lpart)
{
    const int kc = blockIdx.x;          // 0..3   (512-key chunk)
    const int qc = blockIdx.y;          // 0..15  (128-row chunk)
    const int b  = blockIdx.z;
    if (kc > (qc >> 2)) return;
    const int kv_base = kc * 512;
    const int qrel = qc * 128 - kv_base;
    int NT = (qrel >> 6) + 2; if (NT > 8) NT = 8;

    __shared__ unsigned short Ks[2][64 * 128];
    __shared__ unsigned short Vs[2][128 * 64];

    const int tid  = threadIdx.x;
    const int wid  = tid >> 6;
    const int lane = tid & 63;
    const int c5 = lane & 31, hi = lane >> 5;
    const int q0w = qc * 128 + wid * 32;
    const int qg  = q0w + c5;
    const int pidx = b * 40 + part_offs(qc) + kc;

    const short* Kb  = kb  + (size_t)b * TLEN * HDIM;
    const short* Vtb = vtb + (size_t)b * HDIM * TLEN;

    bf16x8 qf[8];
#pragma unroll
    for (int ks = 0; ks < 8; ++ks)
        qf[ks] = *(const bf16x8*)(qb + ((size_t)b * TLEN + qg) * HDIM + ks * 16 + hi * 8);

    bf16x8 kst[4], vst[4];

#define GLOAD(kv0_)                                                          \
    {                                                                        \
        _Pragma("unroll")                                                    \
        for (int it = 0; it < 4; ++it) {                                     \
            const int o = tid * 16 + it * 4096;                              \
            const int kr = o >> 8, kcb = o & 0xF0;                           \
            kst[it] = *(const bf16x8*)((const char*)Kb +                     \
                        (size_t)((kv0_) + kr) * 256 + kcb);                  \
            const int vr = o >> 7, vcb = o & 0x70;                           \
            vst[it] = *(const bf16x8*)((const char*)Vtb +                    \
                        (size_t)vr * (TLEN * 2) + (size_t)(kv0_) * 2 + vcb); \
        }                                                                    \
    }
#define SSTORE(bi_)                                                          \
    {                                                                        \
        _Pragma("unroll")                                                    \
        for (int it = 0; it < 4; ++it) {                                     \
            const int o = tid * 16 + it * 4096;                              \
            const int kr = o >> 8, kcb = o & 0xF0;                           \
            *(bf16x8*)((char*)Ks[bi_] + kr * 256 + (kcb ^ ((kr & 7) << 4))) = kst[it]; \
            const int vr = o >> 7, vcb = o & 0x70;                           \
            *(bf16x8*)((char*)Vs[bi_] + vr * 128 + (vcb ^ ((vr & 7) << 4))) = vst[it]; \
        }                                                                    \
    }

    GLOAD(kv_base);
    SSTORE(0);
    __syncthreads();

    f32x16 oacc[4];
#pragma unroll
    for (int i = 0; i < 4; ++i)
#pragma unroll
        for (int r = 0; r < 16; ++r) oacc[i][r] = 0.f;
    float m_r = -1e30f;
    float l_r = 0.f;

#pragma unroll 1
    for (int t = 0; t < NT; ++t) {
        const int bi = t & 1;
        if (t + 1 < NT) GLOAD(kv_base + 64 * (t + 1));

        const int kv0 = kv_base + 64 * t;
        if (kv0 <= q0w + 31) {
            f32x16 s0, s1;
#pragma unroll
            for (int r = 0; r < 16; ++r) { s0[r] = 0.f; s1[r] = 0.f; }
            __builtin_amdgcn_s_setprio(1);
#pragma unroll
            for (int ks = 0; ks < 8; ++ks) {
                const int col = ks * 32 + hi * 16;
                const int off0 = c5 * 256 + (col ^ ((c5 & 7) << 4));
                const int off1 = (32 + c5) * 256 + (col ^ ((c5 & 7) << 4));
                bf16x8 a0 = *(const bf16x8*)((char*)Ks[bi] + off0);
                bf16x8 a1 = *(const bf16x8*)((char*)Ks[bi] + off1);
                s0 = __builtin_amdgcn_mfma_f32_32x32x16_bf16(a0, qf[ks], s0, 0, 0, 0);
                s1 = __builtin_amdgcn_mfma_f32_32x32x16_bf16(a1, qf[ks], s1, 0, 0, 0);
            }
            __builtin_amdgcn_s_setprio(0);

            if (kv0 + 63 > q0w) {
#pragma unroll
                for (int r = 0; r < 16; ++r) {
                    const int key0 = kv0 + (r & 3) + 8 * (r >> 2) + 4 * hi;
                    if (key0 > qg)      s0[r] = -INFINITY;
                    if (key0 + 32 > qg) s1[r] = -INFINITY;
                }
            }

            float t8[8];
#pragma unroll
            for (int i = 0; i < 8; ++i)
                t8[i] = fmaxf(fmaxf(s0[2*i], s0[2*i+1]), fmaxf(s1[2*i], s1[2*i+1]));
            float smax = fmaxf(fmaxf(fmaxf(t8[0], t8[1]), fmaxf(t8[2], t8[3])),
                               fmaxf(fmaxf(t8[4], t8[5]), fmaxf(t8[6], t8[7])));
            smax = fmaxf(smax, __shfl_xor(smax, 32));

            const bool defer = __all(smax - m_r <= 8.0f);   // T13
            const float mnew = defer ? m_r : fmaxf(m_r, smax);
            if (!defer) {
                const float alpha = __expf(m_r - mnew);
                l_r *= alpha;
#pragma unroll
                for (int hb = 0; hb < 4; ++hb) oacc[hb] = oacc[hb] * alpha;
            }
            m_r = mnew;

#pragma unroll
            for (int r = 0; r < 16; ++r) {
                s0[r] = __expf(s0[r] - mnew);
                s1[r] = __expf(s1[r] - mnew);
            }
            float a8[8];
#pragma unroll
            for (int i = 0; i < 8; ++i)
                a8[i] = (s0[2*i] + s0[2*i+1]) + (s1[2*i] + s1[2*i+1]);
            float psum = ((a8[0] + a8[1]) + (a8[2] + a8[3])) +
                         ((a8[4] + a8[5]) + (a8[6] + a8[7]));
            psum += __shfl_xor(psum, 32);
            l_r += psum;

            bf16x8 pa[4];
#pragma unroll
            for (int kb2 = 0; kb2 < 2; ++kb2) {
#pragma unroll
                for (int par = 0; par < 2; ++par) {
                    const int e = par * 8;
                    float v0, v1, v2, v3, v4, v5, v6, v7;
                    if (kb2 == 0) {
                        v0=s0[e+0]; v1=s0[e+1]; v2=s0[e+2]; v3=s0[e+3];
                        v4=s0[e+4]; v5=s0[e+5]; v6=s0[e+6]; v7=s0[e+7];
                    } else {
                        v0=s1[e+0]; v1=s1[e+1]; v2=s1[e+2]; v3=s1[e+3];
                        v4=s1[e+4]; v5=s1[e+5]; v6=s1[e+6]; v7=s1[e+7];
                    }
                    const unsigned w0 = pkbf(v0, v1), w1 = pkbf(v2, v3);
                    const unsigned w2 = pkbf(v4, v5), w3 = pkbf(v6, v7);
                    const unsigned X0 = hi ? w0 : w2;
                    const unsigned X1 = hi ? w1 : w3;
                    const unsigned R0 = (unsigned)__shfl_xor((int)X0, 32);
                    const unsigned R1 = (unsigned)__shfl_xor((int)X1, 32);
                    union { unsigned w[4]; bf16x8 v; } uu;
                    uu.w[0] = hi ? R0 : w0;  uu.w[1] = hi ? R1 : w1;
                    uu.w[2] = hi ? w2 : R0;  uu.w[3] = hi ? w3 : R1;
                    pa[kb2 * 2 + par] = uu.v;
                }
            }

            __builtin_amdgcn_s_setprio(1);
#pragma unroll
            for (int hb = 0; hb < 4; ++hb) {
                const int row = hb * 32 + c5;
#pragma unroll
                for (int ks = 0; ks < 4; ++ks) {
                    const int off = row * 128 + ((ks * 32 + hi * 16) ^ ((row & 7) << 4));
                    bf16x8 va = *(const bf16x8*)((char*)Vs[bi] + off);
                    oacc[hb] = __builtin_amdgcn_mfma_f32_32x32x16_bf16(va, pa[ks], oacc[hb], 0, 0, 0);
                }
            }
            __builtin_amdgcn_s_setprio(0);
        }

        if (t + 1 < NT) {
            SSTORE(bi ^ 1);
            __syncthreads();
        }
    }

    // ---- epilogue: transpose O via LDS, store partials bf16 ----
    __syncthreads();
    char* sl = (char*)Ks + wid * 8192;
#pragma unroll
    for (int hb = 0; hb < 4; ++hb)
#pragma unroll
        for (int rq = 0; rq < 4; ++rq) {
            u16x4 o4;
            o4[0] = f2bf(oacc[hb][rq * 4 + 0]);
            o4[1] = f2bf(oacc[hb][rq * 4 + 1]);
            o4[2] = f2bf(oacc[hb][rq * 4 + 2]);
            o4[3] = f2bf(oacc[hb][rq * 4 + 3]);
            const int off = c5 * 256 + ((hb * 64 + rq * 16 + hi * 8) ^ ((c5 & 7) << 4));
            *(u16x4*)(sl + off) = o4;
        }
    asm volatile("s_waitcnt lgkmcnt(0)" ::: "memory");
    __builtin_amdgcn_sched_barrier(0);

    const int qr = lane >> 1, hf = lane & 1;
    unsigned short* Og = Opart + (size_t)pidx * 128 * 128 +
                         (size_t)(wid * 32 + qr) * 128 + hf * 64;
#pragma unroll
    for (int i = 0; i < 8; ++i) {
        const int off = qr * 256 + ((hf * 128 + i * 16) ^ ((qr & 7) << 4));
        *(u16x8*)(Og + i * 8) = *(const u16x8*)(sl + off);
    }
    if (hi == 0) {
        mpart[(size_t)pidx * 128 + wid * 32 + c5] = m_r;
        lpart[(size_t)pidx * 128 + wid * 32 + c5] = l_r;
    }
#undef GLOAD
#undef SSTORE
}

// ---------------------------------------------------------------------------
// Kernel 2b: combine partials (r17; n <= 4, m/l register-cached).
// ---------------------------------------------------------------------------
__global__ __launch_bounds__(256) void attn_combine(
    const unsigned short* __restrict__ Opart, const float* __restrict__ mpart,
    const float* __restrict__ lpart, float* __restrict__ out)
{
    const int qc = blockIdx.x;
    const int b  = blockIdx.y;
    const int n  = (qc >> 2) + 1;
    const int base = b * 40 + part_offs(qc);
    const int t   = threadIdx.x;
    const int row = t >> 1;
    const int d0  = (t & 1) * 64;

    float mv[4], lv[4];
#pragma unroll
    for (int p = 0; p < 4; ++p) {
        mv[p] = (p < n) ? mpart[(size_t)(base + p) * 128 + row] : -INFINITY;
        lv[p] = (p < n) ? lpart[(size_t)(base + p) * 128 + row] : 0.f;
    }
    float M = fmaxf(fmaxf(mv[0], mv[1]), fmaxf(mv[2], mv[3]));
    float L = 0.f;
    float wv[4];
#pragma unroll
    for (int p = 0; p < 4; ++p) {
        wv[p] = (p < n) ? __expf(mv[p] - M) : 0.f;
        L += wv[p] * lv[p];
    }

    float acc[64];
#pragma unroll
    for (int i = 0; i < 64; ++i) acc[i] = 0.f;

    for (int p = 0; p < n; ++p) {
        const float w = wv[p];
        const bf16x8* src = (const bf16x8*)(Opart +
            ((size_t)(base + p) * 128 + row) * 128 + d0);
#pragma unroll
        for (int j = 0; j < 8; ++j) {
            bf16x8 v = src[j];
#pragma unroll
            for (int e = 0; e < 8; ++e) {
                union { unsigned u; float f; } xx;
                xx.u = ((unsigned)(unsigned short)v[e]) << 16;
                acc[j * 8 + e] += w * xx.f;
            }
        }
    }

    const float invL = 1.f / L;
    float4* dst = (float4*)(out + ((size_t)(b * TLEN + qc * 128 + row)) * 128 + d0);
#pragma unroll
    for (int i = 0; i < 16; ++i)
        dst[i] = make_float4(acc[4*i] * invL, acc[4*i+1] * invL,
                             acc[4*i+2] * invL, acc[4*i+3] * invL);
}

extern "C" void kernel_launch(void* const* d_in, const int* in_sizes, int n_in,
                              void* d_out, int out_size, void* d_ws, size_t ws_size,
                              hipStream_t stream)
{
    const float* x  = (const float*)d_in[0];
    const float* Wq = (const float*)d_in[1];
    const float* Wk = (const float*)d_in[2];
    const float* Wv = (const float*)d_in[3];
    float* outp = (float*)d_out;

    const size_t per = (size_t)BATCH * TLEN * HDIM;      // 4,194,304
    unsigned short* qb  = (unsigned short*)d_ws;
    unsigned short* kb  = qb + per;
    unsigned short* vtb = kb + per;
    unsigned short* wtb = vtb + per;                     // 384*1024 bf16
    unsigned short* Opart = wtb + 384 * 1024;            // 640*128*128 bf16
    float* mpart = (float*)(Opart + (size_t)640 * 128 * 128);
    float* lpart = mpart + (size_t)640 * 128;

    dim3 gw(512, 3);
    pack_w<<<gw, 256, 0, stream>>>(Wq, Wk, Wv, wtb);

    qkv_fused<<<512, 512, 0, stream>>>(x, wtb, qb, kb, vtb);

    dim3 g2(4, 16, BATCH);
    attn_partial<<<g2, 256, 0, stream>>>((const short*)qb, (const short*)kb,
                                         (const short*)vtb, Opart, mpart, lpart);

    dim3 g3(16, BATCH);
    attn_combine<<<g3, 256, 0, stream>>>(Opart, mpart, lpart, outp);
}